// Round 1
// baseline (1869.688 us; speedup 1.0000x reference)
//
#include <hip/hip_runtime.h>

#define L_SEQ 2048
#define C_IN  64
#define HH    128
#define NSEQ  32
#define B2    64     // 2*NSEQ sequences (fwd + rev)
#define G3    384    // 3*H
#define T_TILE 64

__device__ __forceinline__ float fast_sigmoid(float x) {
    // 1/(1+2^(-x*log2e)); safe at both infinities (rcp(inf)=0)
    float e = __builtin_amdgcn_exp2f(-1.4426950408889634f * x);
    return __builtin_amdgcn_rcpf(1.0f + e);
}

__device__ __forceinline__ float fast_tanh(float x) {
    float a = fabsf(x);
    float e = __builtin_amdgcn_exp2f(-2.8853900817779268f * a); // e^{-2a}
    float r = (1.0f - e) * __builtin_amdgcn_rcpf(1.0f + e);
    return copysignf(r, x);
}

// ---------------------------------------------------------------------------
// Kernel 1: xw[s][tt][j] = b_ih[j] + sum_c xb[s][t0+tt][c] * W_ih[c][j]
// s<32: xb = x[s]; s>=32: xb = ragged-reversed x[s-32] (zeros past length).
// Grid: (steps/T_TILE)*B2 blocks, 384 threads (thread = output column j).
// ---------------------------------------------------------------------------
__global__ __launch_bounds__(384)
void xw_kernel(const float* __restrict__ x, const int* __restrict__ lengths,
               const float* __restrict__ W_ih, const float* __restrict__ b_ih,
               float* __restrict__ xw, int t0, int chunk_steps)
{
    __shared__ float4 xs[T_TILE][16];   // 16 KB
    const int tid = threadIdx.x;
    const int tilesPerSeq = chunk_steps / T_TILE;
    const int s    = blockIdx.x / tilesPerSeq;
    const int tile = blockIdx.x % tilesPerSeq;
    const int tbase = t0 + tile * T_TILE;          // global t of row 0

    const int len = (s >= NSEQ) ? lengths[s - NSEQ] : 0;

    // cooperative staging of T_TILE input rows (reversed/zero-padded for s>=32)
    for (int i = tid; i < T_TILE * 16; i += 384) {
        const int r = i >> 4, c = i & 15;
        const int t = tbase + r;
        float4 v = make_float4(0.f, 0.f, 0.f, 0.f);
        if (s < NSEQ) {
            v = *(const float4*)&x[((size_t)s * L_SEQ + t) * C_IN + c * 4];
        } else if (t < len) {
            const int src = len - 1 - t;
            v = *(const float4*)&x[((size_t)(s - NSEQ) * L_SEQ + src) * C_IN + c * 4];
        }
        xs[r][c] = v;
    }

    // per-thread column of W_ih in registers
    const int j = tid;
    float w[64];
#pragma unroll
    for (int q = 0; q < 64; ++q) w[q] = W_ih[q * G3 + j];
    const float bias = b_ih[j];
    __syncthreads();

    const int tloc = tile * T_TILE;                // local row in chunk buffer
    for (int r = 0; r < T_TILE; ++r) {
        float acc = bias;
#pragma unroll
        for (int c4 = 0; c4 < 16; ++c4) {
            const float4 v = xs[r][c4];
            acc += v.x * w[4*c4+0] + v.y * w[4*c4+1]
                 + v.z * w[4*c4+2] + v.w * w[4*c4+3];
        }
        xw[((size_t)s * chunk_steps + (tloc + r)) * G3 + j] = acc;
    }
}

// ---------------------------------------------------------------------------
// Kernel 2: the GRU recurrence. 64 blocks (one per sequence), 256 threads.
// Thread tid: column j = tid>>1 (owns r,z,n gates), K-half p = tid&1.
// W_hh columns in registers; h double-buffered in LDS; ONE barrier per step.
// ---------------------------------------------------------------------------
__global__ __launch_bounds__(256, 1)
void gru_kernel(const float* __restrict__ xw, const float* __restrict__ W_hh,
                const float* __restrict__ b_hh, float* __restrict__ out,
                float* __restrict__ hstate, int t0, int chunk_steps)
{
    __shared__ float hbuf[2][HH];
    const int s   = blockIdx.x;
    const int tid = threadIdx.x;
    const int j   = tid >> 1;     // 0..127
    const int p   = tid & 1;      // K half: p=0 -> k in [0,64), p=1 -> [64,128)

    // load W_hh[64p+q][col] for col in {j, 128+j, 256+j}
    float wr[64], wz[64], wn[64];
    const float* Wb = W_hh + (size_t)(64 * p) * G3;
#pragma unroll
    for (int q = 0; q < 64; ++q) {
        wr[q] = Wb[q * G3 + j];
        wz[q] = Wb[q * G3 + 128 + j];
        wn[q] = Wb[q * G3 + 256 + j];
    }
    const float br = (p == 0) ? b_hh[j]       : 0.f;
    const float bz = (p == 0) ? b_hh[128 + j] : 0.f;
    const float bn = (p == 0) ? b_hh[256 + j] : 0.f;

    if (tid < HH) hbuf[0][tid] = (t0 == 0) ? 0.f : hstate[s * HH + tid];
    __syncthreads();

    const float* xwp = xw + (size_t)s * chunk_steps * G3;
    // prefetch t = 0
    float xr = xwp[j], xz = xwp[128 + j], xn = xwp[256 + j];

    float* outbase = out + (size_t)(s % NSEQ) * L_SEQ * 256 + ((s < NSEQ) ? 0 : HH);
    int cur = 0;

    for (int t = 0; t < chunk_steps; ++t) {
        // prefetch next step's xw (clamped; latency hides under FMA phase)
        const int tn = (t + 1 < chunk_steps) ? (t + 1) : (chunk_steps - 1);
        const float* qp = xwp + (size_t)tn * G3;
        const float nr = qp[j], nz = qp[128 + j], nn = qp[256 + j];

        float ar = br, az = bz, an = bn;
        const float4* h4 = (const float4*)&hbuf[cur][p * 64];
#pragma unroll
        for (int c = 0; c < 16; ++c) {
            const float4 hv = h4[c];
            ar += hv.x * wr[4*c+0] + hv.y * wr[4*c+1] + hv.z * wr[4*c+2] + hv.w * wr[4*c+3];
            az += hv.x * wz[4*c+0] + hv.y * wz[4*c+1] + hv.z * wz[4*c+2] + hv.w * wz[4*c+3];
            an += hv.x * wn[4*c+0] + hv.y * wn[4*c+1] + hv.z * wn[4*c+2] + hv.w * wn[4*c+3];
        }
        // combine K halves: even/odd lane pair
        ar += __shfl_xor(ar, 1);
        az += __shfl_xor(az, 1);
        an += __shfl_xor(an, 1);

        const float h_old = hbuf[cur][j];
        const float r = fast_sigmoid(xr + ar);
        const float z = fast_sigmoid(xz + az);
        const float n = fast_tanh(xn + r * an);
        const float hnew = z * (h_old - n) + n;

        if (p == 0) {
            hbuf[cur ^ 1][j] = hnew;
            outbase[(size_t)(t0 + t) * 256 + j] = hnew;
        }
        __syncthreads();   // single barrier per step (h is double-buffered)
        cur ^= 1;
        xr = nr; xz = nz; xn = nn;
    }

    if (t0 + chunk_steps < L_SEQ) {
        if (tid < HH) hstate[s * HH + tid] = hbuf[cur][tid];
    }
}

// ---------------------------------------------------------------------------
extern "C" void kernel_launch(void* const* d_in, const int* in_sizes, int n_in,
                              void* d_out, int out_size, void* d_ws, size_t ws_size,
                              hipStream_t stream) {
    const float* x       = (const float*)d_in[0];
    const int*   lengths = (const int*)  d_in[1];
    const float* W_ih    = (const float*)d_in[2];
    const float* W_hh    = (const float*)d_in[3];
    const float* b_ih    = (const float*)d_in[4];
    const float* b_hh    = (const float*)d_in[5];
    float* out = (float*)d_out;

    // ws layout: [hstate: B2*HH floats][xw chunk buffer: rest]
    float* hstate = (float*)d_ws;
    float* xw     = hstate + B2 * HH;
    const size_t per_step = (size_t)B2 * G3 * sizeof(float);       // 98304 B
    size_t avail = (ws_size > (size_t)B2 * HH * sizeof(float))
                 ? ws_size - (size_t)B2 * HH * sizeof(float) : 0;
    long long csteps = (long long)(avail / per_step);
    int chunk;
    if (csteps >= L_SEQ)      chunk = L_SEQ;                        // single pass
    else if (csteps >= T_TILE) chunk = (int)((csteps / T_TILE) * T_TILE);
    else                       chunk = T_TILE;                      // best effort

    for (int t0 = 0; t0 < L_SEQ; t0 += chunk) {
        const int steps = (L_SEQ - t0 < chunk) ? (L_SEQ - t0) : chunk;
        xw_kernel<<<dim3((steps / T_TILE) * B2), dim3(384), 0, stream>>>(
            x, lengths, W_ih, b_ih, xw, t0, steps);
        gru_kernel<<<dim3(B2), dim3(256), 0, stream>>>(
            xw, W_hh, b_hh, out, hstate, t0, steps);
    }
}

// Round 2
// 1521.324 us; speedup vs baseline: 1.2290x; 1.2290x over previous
//
#include <hip/hip_runtime.h>

#define L_SEQ 2048
#define C_IN  64
#define HH    128
#define NSEQ  32
#define B2    64     // 2*NSEQ sequences (fwd + rev)
#define G3    384    // 3*H
#define T_TILE 128

__device__ __forceinline__ float fast_sigmoid(float x) {
    // 1/(1+2^(-x*log2e)); safe at both infinities (rcp(inf)=0)
    float e = __builtin_amdgcn_exp2f(-1.4426950408889634f * x);
    return __builtin_amdgcn_rcpf(1.0f + e);
}

__device__ __forceinline__ float fast_tanh(float x) {
    float a = fabsf(x);
    float e = __builtin_amdgcn_exp2f(-2.8853900817779268f * a); // e^{-2a}
    float r = (1.0f - e) * __builtin_amdgcn_rcpf(1.0f + e);
    return copysignf(r, x);
}

// ---------------------------------------------------------------------------
// Kernel 1: xw[s][tt][j] = b_ih[j] + sum_c xb[s][t0+tt][c] * W_ih[c][j]
// s<32: xb = x[s]; s>=32: xb = ragged-reversed x[s-32] (zeros past length).
// Grid: (steps/T_TILE)*B2 blocks, 384 threads (thread = output column j).
// ---------------------------------------------------------------------------
__global__ __launch_bounds__(384)
void xw_kernel(const float* __restrict__ x, const int* __restrict__ lengths,
               const float* __restrict__ W_ih, const float* __restrict__ b_ih,
               float* __restrict__ xw, int t0, int chunk_steps)
{
    __shared__ float4 xs[T_TILE][16];   // 32 KB
    const int tid = threadIdx.x;
    const int tilesPerSeq = chunk_steps / T_TILE;
    const int s    = blockIdx.x / tilesPerSeq;
    const int tile = blockIdx.x % tilesPerSeq;
    const int tbase = t0 + tile * T_TILE;          // global t of row 0

    const int len = (s >= NSEQ) ? lengths[s - NSEQ] : 0;

    // cooperative staging of T_TILE input rows (reversed/zero-padded for s>=32)
    for (int i = tid; i < T_TILE * 16; i += 384) {
        const int r = i >> 4, c = i & 15;
        const int t = tbase + r;
        float4 v = make_float4(0.f, 0.f, 0.f, 0.f);
        if (s < NSEQ) {
            v = *(const float4*)&x[((size_t)s * L_SEQ + t) * C_IN + c * 4];
        } else if (t < len) {
            const int src = len - 1 - t;
            v = *(const float4*)&x[((size_t)(s - NSEQ) * L_SEQ + src) * C_IN + c * 4];
        }
        xs[r][c] = v;
    }

    // per-thread column of W_ih in registers
    const int j = tid;
    float w[64];
#pragma unroll
    for (int q = 0; q < 64; ++q) w[q] = W_ih[q * G3 + j];
    const float bias = b_ih[j];
    __syncthreads();

    const int tloc = tile * T_TILE;                // local row in chunk buffer
    for (int r = 0; r < T_TILE; ++r) {
        float acc = bias;
#pragma unroll
        for (int c4 = 0; c4 < 16; ++c4) {
            const float4 v = xs[r][c4];
            acc += v.x * w[4*c4+0] + v.y * w[4*c4+1]
                 + v.z * w[4*c4+2] + v.w * w[4*c4+3];
        }
        xw[((size_t)s * chunk_steps + (tloc + r)) * G3 + j] = acc;
    }
}

// ---------------------------------------------------------------------------
// Kernel 2: the GRU recurrence. 64 blocks (one per sequence), 512 threads.
// Thread tid: column j = tid>>2 (owns r,z,n gates), K-quarter p = tid&3.
// 96 weight floats/thread (register-resident, no spill); h double-buffered in
// LDS with 36-float chunk padding (conflict-free ds_read_b128); xw prefetched
// 4 steps ahead in statically-indexed register groups; ONE barrier per step.
// ---------------------------------------------------------------------------
#define HPAD 36   // 32-float K-chunk padded to 36 -> 4 quarter-bases on banks {0,4,8,12}

__global__ __launch_bounds__(512, 2)
void gru_kernel(const float* __restrict__ xw, const float* __restrict__ W_hh,
                const float* __restrict__ b_hh, float* __restrict__ out,
                float* __restrict__ hstate, int t0, int chunk_steps)
{
    __shared__ float hbuf[2][4 * HPAD];      // 2 x 144 floats
    const int s   = blockIdx.x;
    const int tid = threadIdx.x;
    const int j   = tid >> 2;     // 0..127 output column
    const int p   = tid & 3;      // K quarter: k in [32p, 32p+32)

    // load W_hh[32p+q][col] for col in {j, 128+j, 256+j}: 96 floats/thread
    float wr[32], wz[32], wn[32];
    const float* Wb = W_hh + (size_t)(32 * p) * G3;
#pragma unroll
    for (int q = 0; q < 32; ++q) {
        wr[q] = Wb[q * G3 + j];
        wz[q] = Wb[q * G3 + 128 + j];
        wn[q] = Wb[q * G3 + 256 + j];
    }
    const float br = (p == 0) ? b_hh[j]       : 0.f;
    const float bz = (p == 0) ? b_hh[128 + j] : 0.f;
    const float bn = (p == 0) ? b_hh[256 + j] : 0.f;

    if (tid < HH) {
        const float hv = (t0 == 0) ? 0.f : hstate[s * HH + tid];
        hbuf[0][(tid >> 5) * HPAD + (tid & 31)] = hv;
    }
    __syncthreads();

    const float* xwp = xw + (size_t)s * chunk_steps * G3;
    // preload group 0 (steps 0..3)
    float cr[4], cz[4], cn[4];
#pragma unroll
    for (int u = 0; u < 4; ++u) {
        const float* qp = xwp + (size_t)u * G3;
        cr[u] = qp[j]; cz[u] = qp[128 + j]; cn[u] = qp[256 + j];
    }

    float* outbase = out + (size_t)(s % NSEQ) * L_SEQ * 256 + ((s < NSEQ) ? 0 : HH);
    const int hoff = p * HPAD;
    const int jidx = (j >> 5) * HPAD + (j & 31);
    int cur = 0;

    for (int t = 0; t < chunk_steps; t += 4) {
        // issue next group's xw loads now; consumed 4 steps (~1600+ cyc) later
        const int tnb = (t + 4 < chunk_steps) ? (t + 4) : t;   // clamp (dead values)
        float nr[4], nz[4], nn[4];
#pragma unroll
        for (int u = 0; u < 4; ++u) {
            const float* qp = xwp + (size_t)(tnb + u) * G3;
            nr[u] = qp[j]; nz[u] = qp[128 + j]; nn[u] = qp[256 + j];
        }

#pragma unroll
        for (int u = 0; u < 4; ++u) {
            float ar = br, az = bz, an = bn;
            const float4* h4 = (const float4*)&hbuf[cur][hoff];
#pragma unroll
            for (int c = 0; c < 8; ++c) {
                const float4 hv = h4[c];
                ar += hv.x * wr[4*c+0] + hv.y * wr[4*c+1] + hv.z * wr[4*c+2] + hv.w * wr[4*c+3];
                az += hv.x * wz[4*c+0] + hv.y * wz[4*c+1] + hv.z * wz[4*c+2] + hv.w * wz[4*c+3];
                an += hv.x * wn[4*c+0] + hv.y * wn[4*c+1] + hv.z * wn[4*c+2] + hv.w * wn[4*c+3];
            }
            // combine the 4 K-quarters (lanes differing in bits 0,1)
            ar += __shfl_xor(ar, 1);  ar += __shfl_xor(ar, 2);
            az += __shfl_xor(az, 1);  az += __shfl_xor(az, 2);
            an += __shfl_xor(an, 1);  an += __shfl_xor(an, 2);

            const float h_old = hbuf[cur][jidx];
            const float r = fast_sigmoid(cr[u] + ar);
            const float z = fast_sigmoid(cz[u] + az);
            const float n = fast_tanh(cn[u] + r * an);
            const float hnew = z * (h_old - n) + n;

            if (p == 0) {
                hbuf[cur ^ 1][jidx] = hnew;
                outbase[(size_t)(t0 + t + u) * 256 + j] = hnew;
            }
            __syncthreads();   // single barrier per step (h double-buffered)
            cur ^= 1;
        }
#pragma unroll
        for (int u = 0; u < 4; ++u) { cr[u] = nr[u]; cz[u] = nz[u]; cn[u] = nn[u]; }
    }

    if (t0 + chunk_steps < L_SEQ) {
        if (tid < HH) hstate[s * HH + tid] = hbuf[cur][(tid >> 5) * HPAD + (tid & 31)];
    }
}

// ---------------------------------------------------------------------------
extern "C" void kernel_launch(void* const* d_in, const int* in_sizes, int n_in,
                              void* d_out, int out_size, void* d_ws, size_t ws_size,
                              hipStream_t stream) {
    const float* x       = (const float*)d_in[0];
    const int*   lengths = (const int*)  d_in[1];
    const float* W_ih    = (const float*)d_in[2];
    const float* W_hh    = (const float*)d_in[3];
    const float* b_ih    = (const float*)d_in[4];
    const float* b_hh    = (const float*)d_in[5];
    float* out = (float*)d_out;

    // ws layout: [hstate: B2*HH floats][xw chunk buffer: rest]
    float* hstate = (float*)d_ws;
    float* xw     = hstate + B2 * HH;
    const size_t per_step = (size_t)B2 * G3 * sizeof(float);       // 98304 B
    size_t avail = (ws_size > (size_t)B2 * HH * sizeof(float))
                 ? ws_size - (size_t)B2 * HH * sizeof(float) : 0;
    long long csteps = (long long)(avail / per_step);
    int chunk;
    if (csteps >= L_SEQ)       chunk = L_SEQ;                       // single pass
    else if (csteps >= T_TILE) chunk = (int)((csteps / T_TILE) * T_TILE);
    else                       chunk = T_TILE;                      // best effort

    for (int t0 = 0; t0 < L_SEQ; t0 += chunk) {
        const int steps = (L_SEQ - t0 < chunk) ? (L_SEQ - t0) : chunk;
        xw_kernel<<<dim3((steps / T_TILE) * B2), dim3(384), 0, stream>>>(
            x, lengths, W_ih, b_ih, xw, t0, steps);
        gru_kernel<<<dim3(B2), dim3(512), 0, stream>>>(
            xw, W_hh, b_hh, out, hstate, t0, steps);
    }
}

// Round 3
// 1275.719 us; speedup vs baseline: 1.4656x; 1.1925x over previous
//
#include <hip/hip_runtime.h>

#define L_SEQ 2048
#define C_IN  64
#define HH    128
#define NSEQ  32
#define B2    64     // 2*NSEQ sequences (fwd + rev)
#define G3    384    // 3*H
#define T_TILE 128

typedef _Float16 half2_t __attribute__((ext_vector_type(2)));

__device__ __forceinline__ float fdot2u(unsigned int a, unsigned int b, float c) {
    return __builtin_amdgcn_fdot2(__builtin_bit_cast(half2_t, a),
                                  __builtin_bit_cast(half2_t, b), c, false);
}

__device__ __forceinline__ unsigned int pack_h2(float a, float b) {
    half2_t t; t.x = (_Float16)a; t.y = (_Float16)b;
    return __builtin_bit_cast(unsigned int, t);
}

__device__ __forceinline__ float fast_sigmoid(float x) {
    float e = __builtin_amdgcn_exp2f(-1.4426950408889634f * x);
    return __builtin_amdgcn_rcpf(1.0f + e);
}

__device__ __forceinline__ float fast_tanh(float x) {
    float a = fabsf(x);
    float e = __builtin_amdgcn_exp2f(-2.8853900817779268f * a); // e^{-2a}
    float r = (1.0f - e) * __builtin_amdgcn_rcpf(1.0f + e);
    return copysignf(r, x);
}

// ---------------------------------------------------------------------------
// Kernel 1: xw[s][tt][j] = b_ih[j] + sum_c xb[s][t0+tt][c] * W_ih[c][j]
// x rows are block-uniform -> xrow[q] becomes scalar s_load broadcast
// (SGPR operand in v_fma). No LDS at all. 384 threads, thread = column j.
// ---------------------------------------------------------------------------
__global__ __launch_bounds__(384)
void xw_kernel(const float* __restrict__ x, const int* __restrict__ lengths,
               const float* __restrict__ W_ih, const float* __restrict__ b_ih,
               float* __restrict__ xw, int t0, int chunk_steps)
{
    const int tid = threadIdx.x;
    const int tilesPerSeq = chunk_steps / T_TILE;
    const int s    = blockIdx.x / tilesPerSeq;
    const int tile = blockIdx.x % tilesPerSeq;
    const int tbase = t0 + tile * T_TILE;          // global t of row 0

    const int len = (s >= NSEQ) ? lengths[s - NSEQ] : 0;

    const int j = tid;
    float w[64];
#pragma unroll
    for (int q = 0; q < 64; ++q) w[q] = W_ih[q * G3 + j];
    const float bias = b_ih[j];

    const int tloc = tile * T_TILE;
    for (int r = 0; r < T_TILE; ++r) {
        const int t = tbase + r;
        float acc = bias;
        if (s < NSEQ) {
            const float* __restrict__ xrow = x + ((size_t)s * L_SEQ + t) * C_IN;
#pragma unroll
            for (int q = 0; q < 64; ++q) acc += xrow[q] * w[q];
        } else if (t < len) {
            const float* __restrict__ xrow =
                x + ((size_t)(s - NSEQ) * L_SEQ + (len - 1 - t)) * C_IN;
#pragma unroll
            for (int q = 0; q < 64; ++q) acc += xrow[q] * w[q];
        }
        xw[((size_t)s * chunk_steps + (tloc + r)) * G3 + j] = acc;
    }
}

// ---------------------------------------------------------------------------
// Kernel 2: GRU recurrence. 64 blocks (one per sequence), 512 threads.
// Thread tid: column j = tid>>2 (r,z,n gates), K-quarter p = tid&3.
// f16-pair weights (48 u32 regs, register-resident), f16 h in LDS (whole h =
// 256 B, 4 ds_read_b128/thread/step), v_dot2_f32_f16 MACs (half the VALU),
// h_old carried in f32 register, ONE barrier per step.
// ---------------------------------------------------------------------------
__global__ __launch_bounds__(512, 2)
void gru_kernel(const float* __restrict__ xw, const float* __restrict__ W_hh,
                const float* __restrict__ b_hh, float* __restrict__ out,
                float* __restrict__ hstate, int t0, int chunk_steps)
{
    __shared__ unsigned int hbufu[2][64];   // 128 f16 per buffer
    const int s   = blockIdx.x;
    const int tid = threadIdx.x;
    const int j   = tid >> 2;     // 0..127 output column
    const int p   = tid & 3;      // K quarter: k in [32p, 32p+32)

    // packed f16-pair weights: W_hh[32p+2q .. +1][col], col in {j,128+j,256+j}
    unsigned int wr[16], wz[16], wn[16];
    const float* Wb = W_hh + (size_t)(32 * p) * G3;
#pragma unroll
    for (int q = 0; q < 16; ++q) {
        wr[q] = pack_h2(Wb[(2*q) * G3 + j],       Wb[(2*q+1) * G3 + j]);
        wz[q] = pack_h2(Wb[(2*q) * G3 + 128 + j], Wb[(2*q+1) * G3 + 128 + j]);
        wn[q] = pack_h2(Wb[(2*q) * G3 + 256 + j], Wb[(2*q+1) * G3 + 256 + j]);
    }
    const float br = b_hh[j], bz = b_hh[128 + j], bn = b_hh[256 + j];

    float hreg = (t0 == 0) ? 0.f : hstate[s * HH + j];   // own column's h (f32)
    if (tid < HH) {
        const float hv = (t0 == 0) ? 0.f : hstate[s * HH + tid];
        ((_Float16*)&hbufu[0][0])[tid] = (_Float16)hv;
    }
    __syncthreads();

    const float* xwp = xw + (size_t)s * chunk_steps * G3;
    float cr[4], cz[4], cn[4];
#pragma unroll
    for (int u = 0; u < 4; ++u) {
        const float* qp = xwp + (size_t)u * G3;
        cr[u] = qp[j]; cz[u] = qp[128 + j]; cn[u] = qp[256 + j];
    }

    float* outbase = out + (size_t)(s % NSEQ) * L_SEQ * 256 + ((s < NSEQ) ? 0 : HH);
    int cur = 0;

    for (int t = 0; t < chunk_steps; t += 4) {
        const int tnb = (t + 4 < chunk_steps) ? (t + 4) : t;   // clamp (dead)
        float nr[4], nz[4], nn[4];
#pragma unroll
        for (int u = 0; u < 4; ++u) {
            const float* qp = xwp + (size_t)(tnb + u) * G3;
            nr[u] = qp[j]; nz[u] = qp[128 + j]; nn[u] = qp[256 + j];
        }

#pragma unroll
        for (int u = 0; u < 4; ++u) {
            float ar = 0.f, az = 0.f, an = 0.f;
            const uint4* hb = (const uint4*)&hbufu[cur][p * 16];
#pragma unroll
            for (int i = 0; i < 4; ++i) {
                const uint4 hv = hb[i];
                ar = fdot2u(hv.x, wr[4*i+0], ar); ar = fdot2u(hv.y, wr[4*i+1], ar);
                ar = fdot2u(hv.z, wr[4*i+2], ar); ar = fdot2u(hv.w, wr[4*i+3], ar);
                az = fdot2u(hv.x, wz[4*i+0], az); az = fdot2u(hv.y, wz[4*i+1], az);
                az = fdot2u(hv.z, wz[4*i+2], az); az = fdot2u(hv.w, wz[4*i+3], az);
                an = fdot2u(hv.x, wn[4*i+0], an); an = fdot2u(hv.y, wn[4*i+1], an);
                an = fdot2u(hv.z, wn[4*i+2], an); an = fdot2u(hv.w, wn[4*i+3], an);
            }
            // combine the 4 K-quarters; afterwards ALL lanes hold full sums
            ar += __shfl_xor(ar, 1);  ar += __shfl_xor(ar, 2);
            az += __shfl_xor(az, 1);  az += __shfl_xor(az, 2);
            an += __shfl_xor(an, 1);  an += __shfl_xor(an, 2);

            const float r = fast_sigmoid(cr[u] + br + ar);
            const float z = fast_sigmoid(cz[u] + bz + az);
            const float n = fast_tanh(cn[u] + r * (an + bn));
            const float hnew = z * (hreg - n) + n;
            hreg = hnew;

            if (p == 0) {
                ((_Float16*)&hbufu[cur ^ 1][0])[j] = (_Float16)hnew;
                outbase[(size_t)(t0 + t + u) * 256 + j] = hnew;
            }
            __syncthreads();   // single barrier per step (h double-buffered)
            cur ^= 1;
        }
#pragma unroll
        for (int u = 0; u < 4; ++u) { cr[u] = nr[u]; cz[u] = nz[u]; cn[u] = nn[u]; }
    }

    if (t0 + chunk_steps < L_SEQ && p == 0) hstate[s * HH + j] = hreg;
}

// ---------------------------------------------------------------------------
extern "C" void kernel_launch(void* const* d_in, const int* in_sizes, int n_in,
                              void* d_out, int out_size, void* d_ws, size_t ws_size,
                              hipStream_t stream) {
    const float* x       = (const float*)d_in[0];
    const int*   lengths = (const int*)  d_in[1];
    const float* W_ih    = (const float*)d_in[2];
    const float* W_hh    = (const float*)d_in[3];
    const float* b_ih    = (const float*)d_in[4];
    const float* b_hh    = (const float*)d_in[5];
    float* out = (float*)d_out;

    // ws layout: [hstate: B2*HH floats][xw chunk buffer: rest]
    float* hstate = (float*)d_ws;
    float* xw     = hstate + B2 * HH;
    const size_t per_step = (size_t)B2 * G3 * sizeof(float);       // 98304 B
    size_t avail = (ws_size > (size_t)B2 * HH * sizeof(float))
                 ? ws_size - (size_t)B2 * HH * sizeof(float) : 0;
    long long csteps = (long long)(avail / per_step);
    int chunk;
    if (csteps >= L_SEQ)       chunk = L_SEQ;                       // single pass
    else if (csteps >= T_TILE) chunk = (int)((csteps / T_TILE) * T_TILE);
    else                       chunk = T_TILE;                      // best effort

    for (int t0 = 0; t0 < L_SEQ; t0 += chunk) {
        const int steps = (L_SEQ - t0 < chunk) ? (L_SEQ - t0) : chunk;
        xw_kernel<<<dim3((steps / T_TILE) * B2), dim3(384), 0, stream>>>(
            x, lengths, W_ih, b_ih, xw, t0, steps);
        gru_kernel<<<dim3(B2), dim3(512), 0, stream>>>(
            xw, W_hh, b_hh, out, hstate, t0, steps);
    }
}

// Round 4
// 1238.226 us; speedup vs baseline: 1.5100x; 1.0303x over previous
//
#include <hip/hip_runtime.h>

#define L_SEQ 2048
#define C_IN  64
#define HH    128
#define NSEQ  32
#define B2    64     // 2*NSEQ sequences (fwd + rev)
#define G3    384    // 3*H
#define T_TILE 128

typedef _Float16 half2_t __attribute__((ext_vector_type(2)));

__device__ __forceinline__ float fdot2u(unsigned int a, unsigned int b, float c) {
    return __builtin_amdgcn_fdot2(__builtin_bit_cast(half2_t, a),
                                  __builtin_bit_cast(half2_t, b), c, false);
}

__device__ __forceinline__ unsigned int pack_h2(float a, float b) {
    half2_t t; t.x = (_Float16)a; t.y = (_Float16)b;
    return __builtin_bit_cast(unsigned int, t);
}

__device__ __forceinline__ float fast_sigmoid(float x) {
    float e = __builtin_amdgcn_exp2f(-1.4426950408889634f * x);
    return __builtin_amdgcn_rcpf(1.0f + e);
}

__device__ __forceinline__ float fast_tanh(float x) {
    float a = fabsf(x);
    float e = __builtin_amdgcn_exp2f(-2.8853900817779268f * a); // e^{-2a}
    float r = (1.0f - e) * __builtin_amdgcn_rcpf(1.0f + e);
    return copysignf(r, x);
}

// ---------------------------------------------------------------------------
// Kernel 1: xw[s][tt][j] = b_ih[j] + sum_c xb[s][t0+tt][c] * W_ih[c][j]
// x rows are block-uniform -> xrow[q] becomes scalar s_load broadcast
// (SGPR operand in v_fma). No LDS at all. 384 threads, thread = column j.
// ---------------------------------------------------------------------------
__global__ __launch_bounds__(384)
void xw_kernel(const float* __restrict__ x, const int* __restrict__ lengths,
               const float* __restrict__ W_ih, const float* __restrict__ b_ih,
               float* __restrict__ xw, int t0, int chunk_steps)
{
    const int tid = threadIdx.x;
    const int tilesPerSeq = chunk_steps / T_TILE;
    const int s    = blockIdx.x / tilesPerSeq;
    const int tile = blockIdx.x % tilesPerSeq;
    const int tbase = t0 + tile * T_TILE;          // global t of row 0

    const int len = (s >= NSEQ) ? lengths[s - NSEQ] : 0;

    const int j = tid;
    float w[64];
#pragma unroll
    for (int q = 0; q < 64; ++q) w[q] = W_ih[q * G3 + j];
    const float bias = b_ih[j];

    const int tloc = tile * T_TILE;
    for (int r = 0; r < T_TILE; ++r) {
        const int t = tbase + r;
        float acc = bias;
        if (s < NSEQ) {
            const float* __restrict__ xrow = x + ((size_t)s * L_SEQ + t) * C_IN;
#pragma unroll
            for (int q = 0; q < 64; ++q) acc += xrow[q] * w[q];
        } else if (t < len) {
            const float* __restrict__ xrow =
                x + ((size_t)(s - NSEQ) * L_SEQ + (len - 1 - t)) * C_IN;
#pragma unroll
            for (int q = 0; q < 64; ++q) acc += xrow[q] * w[q];
        }
        xw[((size_t)s * chunk_steps + (tloc + r)) * G3 + j] = acc;
    }
}

// ---------------------------------------------------------------------------
// Kernel 2: GRU recurrence. 64 blocks (one per sequence), 512 threads.
// Thread tid: column j = tid>>2 (r,z,n gates), K-quarter p = tid&3.
// f16-pair weights in registers, f16 h double-buffered in LDS,
// v_dot2_f32_f16 MACs, raw s_barrier per step: lgkmcnt(0) ONLY — no vmcnt
// drain, so out-stores and 4-deep xw prefetch stay in flight across steps.
// The "memory" clobber also pins the weight loads (no remat across steps).
// ---------------------------------------------------------------------------
__global__ __launch_bounds__(512, 2)
void gru_kernel(const float* __restrict__ xw, const float* __restrict__ W_hh,
                const float* __restrict__ b_hh, float* __restrict__ out,
                float* __restrict__ hstate, int t0, int chunk_steps)
{
    __shared__ unsigned int hbufu[2][64];   // 128 f16 per buffer
    const int s   = blockIdx.x;
    const int tid = threadIdx.x;
    const int j   = tid >> 2;     // 0..127 output column
    const int p   = tid & 3;      // K quarter: k in [32p, 32p+32)

    // packed f16-pair weights: W_hh[32p+2q .. +1][col], col in {j,128+j,256+j}
    unsigned int wr[16], wz[16], wn[16];
    const float* Wb = W_hh + (size_t)(32 * p) * G3;
#pragma unroll
    for (int q = 0; q < 16; ++q) {
        wr[q] = pack_h2(Wb[(2*q) * G3 + j],       Wb[(2*q+1) * G3 + j]);
        wz[q] = pack_h2(Wb[(2*q) * G3 + 128 + j], Wb[(2*q+1) * G3 + 128 + j]);
        wn[q] = pack_h2(Wb[(2*q) * G3 + 256 + j], Wb[(2*q+1) * G3 + 256 + j]);
    }
    const float br = b_hh[j], bz = b_hh[128 + j], bn = b_hh[256 + j];

    float hreg = (t0 == 0) ? 0.f : hstate[s * HH + j];   // own column's h (f32)
    if (tid < HH) {
        const float hv = (t0 == 0) ? 0.f : hstate[s * HH + tid];
        ((_Float16*)&hbufu[0][0])[tid] = (_Float16)hv;
    }
    __syncthreads();

    const float* xwp = xw + (size_t)s * chunk_steps * G3;
    float cr[4], cz[4], cn[4];
#pragma unroll
    for (int u = 0; u < 4; ++u) {
        const float* qp = xwp + (size_t)u * G3;
        cr[u] = qp[j]; cz[u] = qp[128 + j]; cn[u] = qp[256 + j];
    }

    float* outbase = out + (size_t)(s % NSEQ) * L_SEQ * 256 + ((s < NSEQ) ? 0 : HH);
    int cur = 0;

    for (int t = 0; t < chunk_steps; t += 4) {
        const int tnb = (t + 4 < chunk_steps) ? (t + 4) : t;   // clamp (dead)
        float nr[4], nz[4], nn[4];
#pragma unroll
        for (int u = 0; u < 4; ++u) {
            const float* qp = xwp + (size_t)(tnb + u) * G3;
            nr[u] = qp[j]; nz[u] = qp[128 + j]; nn[u] = qp[256 + j];
        }

#pragma unroll
        for (int u = 0; u < 4; ++u) {
            float ar = 0.f, az = 0.f, an = 0.f;
            const uint4* hb = (const uint4*)&hbufu[cur][p * 16];
#pragma unroll
            for (int i = 0; i < 4; ++i) {
                const uint4 hv = hb[i];
                ar = fdot2u(hv.x, wr[4*i+0], ar); ar = fdot2u(hv.y, wr[4*i+1], ar);
                ar = fdot2u(hv.z, wr[4*i+2], ar); ar = fdot2u(hv.w, wr[4*i+3], ar);
                az = fdot2u(hv.x, wz[4*i+0], az); az = fdot2u(hv.y, wz[4*i+1], az);
                az = fdot2u(hv.z, wz[4*i+2], az); az = fdot2u(hv.w, wz[4*i+3], az);
                an = fdot2u(hv.x, wn[4*i+0], an); an = fdot2u(hv.y, wn[4*i+1], an);
                an = fdot2u(hv.z, wn[4*i+2], an); an = fdot2u(hv.w, wn[4*i+3], an);
            }
            // combine the 4 K-quarters; afterwards ALL lanes hold full sums
            ar += __shfl_xor(ar, 1);  ar += __shfl_xor(ar, 2);
            az += __shfl_xor(az, 1);  az += __shfl_xor(az, 2);
            an += __shfl_xor(an, 1);  an += __shfl_xor(an, 2);

            const float r = fast_sigmoid(cr[u] + br + ar);
            const float z = fast_sigmoid(cz[u] + bz + az);
            const float n = fast_tanh(cn[u] + r * (an + bn));
            const float hnew = z * (hreg - n) + n;
            hreg = hnew;

            if (p == 0) {
                ((_Float16*)&hbufu[cur ^ 1][0])[j] = (_Float16)hnew;
                outbase[(size_t)(t0 + t + u) * 256 + j] = hnew;
            }
            // raw barrier: drain LDS only (h exchange); vmcnt stays in flight
            asm volatile("s_waitcnt lgkmcnt(0)\n\ts_barrier" ::: "memory");
            cur ^= 1;
        }
#pragma unroll
        for (int u = 0; u < 4; ++u) { cr[u] = nr[u]; cz[u] = nz[u]; cn[u] = nn[u]; }
    }

    if (t0 + chunk_steps < L_SEQ && p == 0) hstate[s * HH + j] = hreg;
}

// ---------------------------------------------------------------------------
extern "C" void kernel_launch(void* const* d_in, const int* in_sizes, int n_in,
                              void* d_out, int out_size, void* d_ws, size_t ws_size,
                              hipStream_t stream) {
    const float* x       = (const float*)d_in[0];
    const int*   lengths = (const int*)  d_in[1];
    const float* W_ih    = (const float*)d_in[2];
    const float* W_hh    = (const float*)d_in[3];
    const float* b_ih    = (const float*)d_in[4];
    const float* b_hh    = (const float*)d_in[5];
    float* out = (float*)d_out;

    // ws layout: [hstate: B2*HH floats][xw chunk buffer: rest]
    float* hstate = (float*)d_ws;
    float* xw     = hstate + B2 * HH;
    const size_t per_step = (size_t)B2 * G3 * sizeof(float);       // 98304 B
    size_t avail = (ws_size > (size_t)B2 * HH * sizeof(float))
                 ? ws_size - (size_t)B2 * HH * sizeof(float) : 0;
    long long csteps = (long long)(avail / per_step);
    int chunk;
    if (csteps >= L_SEQ)       chunk = L_SEQ;                       // single pass
    else if (csteps >= T_TILE) chunk = (int)((csteps / T_TILE) * T_TILE);
    else                       chunk = T_TILE;                      // best effort

    for (int t0 = 0; t0 < L_SEQ; t0 += chunk) {
        const int steps = (L_SEQ - t0 < chunk) ? (L_SEQ - t0) : chunk;
        xw_kernel<<<dim3((steps / T_TILE) * B2), dim3(384), 0, stream>>>(
            x, lengths, W_ih, b_ih, xw, t0, steps);
        gru_kernel<<<dim3(B2), dim3(512), 0, stream>>>(
            xw, W_hh, b_hh, out, hstate, t0, steps);
    }
}

// Round 5
// 1108.792 us; speedup vs baseline: 1.6862x; 1.1167x over previous
//
#include <hip/hip_runtime.h>

#define L_SEQ 2048
#define C_IN  64
#define HH    128
#define NSEQ  32
#define B2    64     // 2*NSEQ sequences (fwd + rev)
#define G3    384    // 3*H
#define T_TILE 128

typedef _Float16 half2_t __attribute__((ext_vector_type(2)));

// keep a value opaque + register-resident (defeats rematerialization)
#define PINU(v) asm volatile("" : "+v"(v))

__device__ __forceinline__ float fdot2u(unsigned int a, unsigned int b, float c) {
    return __builtin_amdgcn_fdot2(__builtin_bit_cast(half2_t, a),
                                  __builtin_bit_cast(half2_t, b), c, false);
}

__device__ __forceinline__ unsigned int pack_h2(float a, float b) {
    half2_t t; t.x = (_Float16)a; t.y = (_Float16)b;
    return __builtin_bit_cast(unsigned int, t);
}

// quad-perm DPP adds: cross-lane reduce within a lane-quad, pure VALU (no DS)
__device__ __forceinline__ float qadd1(float x) {   // += lane^1
    int t = __builtin_amdgcn_update_dpp(0, __builtin_bit_cast(int, x),
                                        0xB1, 0xF, 0xF, true); // [1,0,3,2]
    return x + __builtin_bit_cast(float, t);
}
__device__ __forceinline__ float qadd2(float x) {   // += lane^2
    int t = __builtin_amdgcn_update_dpp(0, __builtin_bit_cast(int, x),
                                        0x4E, 0xF, 0xF, true); // [2,3,0,1]
    return x + __builtin_bit_cast(float, t);
}

__device__ __forceinline__ float fast_sigmoid(float x) {
    float e = __builtin_amdgcn_exp2f(-1.4426950408889634f * x);
    return __builtin_amdgcn_rcpf(1.0f + e);
}

__device__ __forceinline__ float fast_tanh(float x) {
    float a = fabsf(x);
    float e = __builtin_amdgcn_exp2f(-2.8853900817779268f * a); // e^{-2a}
    float r = (1.0f - e) * __builtin_amdgcn_rcpf(1.0f + e);
    return copysignf(r, x);
}

// ---------------------------------------------------------------------------
// Kernel 1: xw[s][tt][j] = b_ih[j] + sum_c xb[s][t0+tt][c] * W_ih[c][j]
// x rows are block-uniform -> scalar s_load broadcast; W_ih column pinned in
// VGPRs. 384 threads, thread = output column j.
// ---------------------------------------------------------------------------
__global__ __launch_bounds__(384)
void xw_kernel(const float* __restrict__ x, const int* __restrict__ lengths,
               const float* __restrict__ W_ih, const float* __restrict__ b_ih,
               float* __restrict__ xw, int t0, int chunk_steps)
{
    const int tid = threadIdx.x;
    const int tilesPerSeq = chunk_steps / T_TILE;
    const int s    = blockIdx.x / tilesPerSeq;
    const int tile = blockIdx.x % tilesPerSeq;
    const int tbase = t0 + tile * T_TILE;          // global t of row 0

    const int len = (s >= NSEQ) ? lengths[s - NSEQ] : 0;

    const int j = tid;
    float w[64];
#pragma unroll
    for (int q = 0; q < 64; ++q) w[q] = W_ih[q * G3 + j];
#pragma unroll
    for (int q = 0; q < 64; ++q) PINU(w[q]);
    const float bias = b_ih[j];

    const int tloc = tile * T_TILE;
    for (int r = 0; r < T_TILE; ++r) {
        const int t = tbase + r;
        float acc = bias;
        if (s < NSEQ) {
            const float* __restrict__ xrow = x + ((size_t)s * L_SEQ + t) * C_IN;
#pragma unroll
            for (int q = 0; q < 64; ++q) acc += xrow[q] * w[q];
        } else if (t < len) {
            const float* __restrict__ xrow =
                x + ((size_t)(s - NSEQ) * L_SEQ + (len - 1 - t)) * C_IN;
#pragma unroll
            for (int q = 0; q < 64; ++q) acc += xrow[q] * w[q];
        }
        xw[((size_t)s * chunk_steps + (tloc + r)) * G3 + j] = acc;
    }
}

// ---------------------------------------------------------------------------
// Kernel 2: GRU recurrence. 64 blocks (one per sequence), 512 threads.
// Thread tid: column j = tid>>2 (r,z,n gates), K-quarter p = tid&3.
// f16-pair weights PINNED in VGPRs (no remat), f16 h double-buffered in LDS,
// v_dot2_f32_f16 MACs, DPP quad-perm reduce (pure VALU, no DS pipe),
// raw s_barrier per step draining lgkmcnt only (out-stores + 4-deep xw
// prefetch stay in flight).
// ---------------------------------------------------------------------------
__global__ __launch_bounds__(512, 2)
void gru_kernel(const float* __restrict__ xw, const float* __restrict__ W_hh,
                const float* __restrict__ b_hh, float* __restrict__ out,
                float* __restrict__ hstate, int t0, int chunk_steps)
{
    __shared__ unsigned int hbufu[2][64];   // 128 f16 per buffer
    const int s   = blockIdx.x;
    const int tid = threadIdx.x;
    const int j   = tid >> 2;     // 0..127 output column
    const int p   = tid & 3;      // K quarter: k in [32p, 32p+32)

    // packed f16-pair weights: W_hh[32p+2q .. +1][col], col in {j,128+j,256+j}
    unsigned int wr[16], wz[16], wn[16];
    const float* Wb = W_hh + (size_t)(32 * p) * G3;
#pragma unroll
    for (int q = 0; q < 16; ++q) {
        wr[q] = pack_h2(Wb[(2*q) * G3 + j],       Wb[(2*q+1) * G3 + j]);
        wz[q] = pack_h2(Wb[(2*q) * G3 + 128 + j], Wb[(2*q+1) * G3 + 128 + j]);
        wn[q] = pack_h2(Wb[(2*q) * G3 + 256 + j], Wb[(2*q+1) * G3 + 256 + j]);
    }
#pragma unroll
    for (int q = 0; q < 16; ++q) { PINU(wr[q]); PINU(wz[q]); PINU(wn[q]); }
    float br = b_hh[j], bz = b_hh[128 + j], bn = b_hh[256 + j];
    PINU(br); PINU(bz); PINU(bn);

    float hreg = (t0 == 0) ? 0.f : hstate[s * HH + j];   // own column's h (f32)
    if (tid < HH) {
        const float hv = (t0 == 0) ? 0.f : hstate[s * HH + tid];
        ((_Float16*)&hbufu[0][0])[tid] = (_Float16)hv;
    }
    __syncthreads();

    const float* xwp = xw + (size_t)s * chunk_steps * G3;
    float cr[4], cz[4], cn[4];
#pragma unroll
    for (int u = 0; u < 4; ++u) {
        const float* qp = xwp + (size_t)u * G3;
        cr[u] = qp[j]; cz[u] = qp[128 + j]; cn[u] = qp[256 + j];
    }

    float* outbase = out + (size_t)(s % NSEQ) * L_SEQ * 256 + ((s < NSEQ) ? 0 : HH);
    int cur = 0;

    for (int t = 0; t < chunk_steps; t += 4) {
        const int tnb = (t + 4 < chunk_steps) ? (t + 4) : t;   // clamp (dead)
        float nr[4], nz[4], nn[4];
#pragma unroll
        for (int u = 0; u < 4; ++u) {
            const float* qp = xwp + (size_t)(tnb + u) * G3;
            nr[u] = qp[j]; nz[u] = qp[128 + j]; nn[u] = qp[256 + j];
        }

#pragma unroll
        for (int u = 0; u < 4; ++u) {
            float ar = 0.f, az = 0.f, an = 0.f;
            const uint4* hb = (const uint4*)&hbufu[cur][p * 16];
#pragma unroll
            for (int i = 0; i < 4; ++i) {
                const uint4 hv = hb[i];
                ar = fdot2u(hv.x, wr[4*i+0], ar); ar = fdot2u(hv.y, wr[4*i+1], ar);
                ar = fdot2u(hv.z, wr[4*i+2], ar); ar = fdot2u(hv.w, wr[4*i+3], ar);
                az = fdot2u(hv.x, wz[4*i+0], az); az = fdot2u(hv.y, wz[4*i+1], az);
                az = fdot2u(hv.z, wz[4*i+2], az); az = fdot2u(hv.w, wz[4*i+3], az);
                an = fdot2u(hv.x, wn[4*i+0], an); an = fdot2u(hv.y, wn[4*i+1], an);
                an = fdot2u(hv.z, wn[4*i+2], an); an = fdot2u(hv.w, wn[4*i+3], an);
            }
            // combine the 4 K-quarters in-register (DPP quad-perm, no DS pipe)
            ar = qadd1(ar); ar = qadd2(ar);
            az = qadd1(az); az = qadd2(az);
            an = qadd1(an); an = qadd2(an);

            const float r = fast_sigmoid(cr[u] + br + ar);
            const float z = fast_sigmoid(cz[u] + bz + az);
            const float n = fast_tanh(cn[u] + r * (an + bn));
            const float hnew = z * (hreg - n) + n;
            hreg = hnew;

            if (p == 0) {
                ((_Float16*)&hbufu[cur ^ 1][0])[j] = (_Float16)hnew;
                outbase[(size_t)(t0 + t + u) * 256 + j] = hnew;
            }
            // raw barrier: drain LDS only (h exchange); vmcnt stays in flight
            asm volatile("s_waitcnt lgkmcnt(0)\n\ts_barrier" ::: "memory");
            cur ^= 1;
        }
#pragma unroll
        for (int u = 0; u < 4; ++u) { cr[u] = nr[u]; cz[u] = nz[u]; cn[u] = nn[u]; }
    }

    if (t0 + chunk_steps < L_SEQ && p == 0) hstate[s * HH + j] = hreg;
}

// ---------------------------------------------------------------------------
extern "C" void kernel_launch(void* const* d_in, const int* in_sizes, int n_in,
                              void* d_out, int out_size, void* d_ws, size_t ws_size,
                              hipStream_t stream) {
    const float* x       = (const float*)d_in[0];
    const int*   lengths = (const int*)  d_in[1];
    const float* W_ih    = (const float*)d_in[2];
    const float* W_hh    = (const float*)d_in[3];
    const float* b_ih    = (const float*)d_in[4];
    const float* b_hh    = (const float*)d_in[5];
    float* out = (float*)d_out;

    // ws layout: [hstate: B2*HH floats][xw chunk buffer: rest]
    float* hstate = (float*)d_ws;
    float* xw     = hstate + B2 * HH;
    const size_t per_step = (size_t)B2 * G3 * sizeof(float);       // 98304 B
    size_t avail = (ws_size > (size_t)B2 * HH * sizeof(float))
                 ? ws_size - (size_t)B2 * HH * sizeof(float) : 0;
    long long csteps = (long long)(avail / per_step);
    int chunk;
    if (csteps >= L_SEQ)       chunk = L_SEQ;                       // single pass
    else if (csteps >= T_TILE) chunk = (int)((csteps / T_TILE) * T_TILE);
    else                       chunk = T_TILE;                      // best effort

    for (int t0 = 0; t0 < L_SEQ; t0 += chunk) {
        const int steps = (L_SEQ - t0 < chunk) ? (L_SEQ - t0) : chunk;
        xw_kernel<<<dim3((steps / T_TILE) * B2), dim3(384), 0, stream>>>(
            x, lengths, W_ih, b_ih, xw, t0, steps);
        gru_kernel<<<dim3(B2), dim3(512), 0, stream>>>(
            xw, W_hh, b_hh, out, hstate, t0, steps);
    }
}